// Round 1
// baseline (839.858 us; speedup 1.0000x reference)
//
#include <hip/hip_runtime.h>
#include <hip/hip_fp16.h>
#include <cstdint>

#define T_TOK 2048
#define H_DIM 2048
#define I_DIM 768
#define N_EXP 16
#define TOPK  8

typedef _Float16 half8  __attribute__((ext_vector_type(8)));
typedef _Float16 half4v __attribute__((ext_vector_type(4)));
typedef float    f32x4  __attribute__((ext_vector_type(4)));

#define GLDS16(g, l)                                                        \
  __builtin_amdgcn_global_load_lds(                                         \
      (const __attribute__((address_space(1))) unsigned int*)(g),           \
      (__attribute__((address_space(3))) unsigned int*)(l), 16, 0, 0)

// Bit-exact replication of the reference fp4 fake-quant (ties round UP like
// jnp.digitize(right=False)): v = x/scale in f32, snap |v| to e2m1 grid.
__device__ __forceinline__ float fp4_q(float x, float scale) {
  float v = x / scale;
  float a = fabsf(v);
  float q;
  if      (a < 0.25f) q = 0.0f;
  else if (a < 0.75f) q = 0.5f;
  else if (a < 1.25f) q = 1.0f;
  else if (a < 1.75f) q = 1.5f;
  else if (a < 2.5f)  q = 2.0f;
  else if (a < 3.5f)  q = 3.0f;
  else if (a < 5.0f)  q = 4.0f;
  else                q = 6.0f;
  return copysignf(q, v) * scale;
}

__global__ void zero_kernel(float* __restrict__ out, int* __restrict__ counts) {
  int gid = blockIdx.x * 256 + threadIdx.x;
  ((f32x4*)out)[gid] = (f32x4){0.f, 0.f, 0.f, 0.f};
  if (gid < N_EXP) counts[gid] = 0;
}

__global__ void router_kernel(const int* __restrict__ idx, const float* __restrict__ wts,
                              float* __restrict__ w_te, int* __restrict__ counts,
                              int* __restrict__ list) {
  int t = blockIdx.x * 256 + threadIdx.x;
  if (t >= T_TOK) return;
  int   id[TOPK];
  float w[TOPK];
#pragma unroll
  for (int k = 0; k < TOPK; ++k) { id[k] = idx[t * TOPK + k]; w[k] = wts[t * TOPK + k]; }
#pragma unroll
  for (int e = 0; e < N_EXP; ++e) {
    float acc = 0.f;
#pragma unroll
    for (int k = 0; k < TOPK; ++k) acc += (id[k] == e) ? w[k] : 0.0f;
    w_te[t * N_EXP + e] = acc;
    if (acc != 0.0f) {
      int pos = atomicAdd(&counts[e], 1);
      list[e * T_TOK + pos] = t;
    }
  }
}

// One float4 per lane; per-16-element quant block = 4 consecutive lanes.
// Outputs f16 hi (and optional f16 lo residual) for error-free split GEMM.
__global__ void quant_kernel(const float* __restrict__ src, _Float16* __restrict__ dh,
                             _Float16* __restrict__ dl, int n4) {
  int gid = blockIdx.x * 256 + threadIdx.x;
  if (gid >= n4) return;
  f32x4 x = ((const f32x4*)src)[gid];
  float am = fmaxf(fmaxf(fabsf(x[0]), fabsf(x[1])), fmaxf(fabsf(x[2]), fabsf(x[3])));
  am = fmaxf(am, __shfl_xor(am, 1, 64));
  am = fmaxf(am, __shfl_xor(am, 2, 64));
  float scale = am > 0.0f ? am / 6.0f : 1.0f;
  half4v hv, lv;
#pragma unroll
  for (int j = 0; j < 4; ++j) {
    float xq = fp4_q(x[j], scale);
    _Float16 h = (_Float16)xq;
    hv[j] = h;
    lv[j] = (_Float16)(xq - (float)h);
  }
  ((half4v*)dh)[gid] = hv;
  if (dl) ((half4v*)dl)[gid] = lv;
}

// GEMM1: per-expert gathered tokens. 128x64 tile over (tokens x gate-cols),
// up-cols computed in the same block. 3-pass f16 split: Xh*Wh + Xh*Wl + Xl*Wh.
// Epilogue: silu(gate)*up -> bit-exact fp4 fake-quant along INTER -> aq (f16).
__launch_bounds__(256, 2)
__global__ void gemm1_kernel(const _Float16* __restrict__ xh, const _Float16* __restrict__ xl,
                             const _Float16* __restrict__ wh, const _Float16* __restrict__ wl,
                             const int* __restrict__ counts, const int* __restrict__ list,
                             _Float16* __restrict__ aq) {
  __shared__ __align__(16) _Float16 sAh[128 * 64];
  __shared__ __align__(16) _Float16 sAl[128 * 64];
  __shared__ __align__(16) _Float16 sBh[128 * 64];  // rows 0-63 gate, 64-127 up
  __shared__ __align__(16) _Float16 sBl[128 * 64];
  __shared__ int s_tok[128];

  const int e = blockIdx.z, tile = blockIdx.y;
  const int cnt = counts[e];
  const int row0 = tile * 128;
  if (row0 >= cnt) return;
  const int nvalid = min(128, cnt - row0);
  const int n0  = blockIdx.x * 64;
  const int tid = threadIdx.x;
  const int wave = tid >> 6, lane = tid & 63;

  if (tid < 128) {
    int r = (tid < nvalid) ? tid : 0;
    s_tok[tid] = list[e * T_TOK + row0 + r];
  }
  __syncthreads();

  size_t a_byte[4], b_byte[4];
  unsigned lds_off[4];
#pragma unroll
  for (int s = 0; s < 4; ++s) {
    int r = wave * 32 + s * 8 + (lane >> 3);
    int tok = s_tok[r];
    a_byte[s] = ((size_t)tok * H_DIM + (size_t)((lane & 7) * 8)) * 2;
    int grow = (r < 64) ? (e * 2 * I_DIM + n0 + r)
                        : (e * 2 * I_DIM + I_DIM + n0 + (r - 64));
    b_byte[s] = ((size_t)grow * H_DIM + (size_t)((lane & 7) * 8)) * 2;
    lds_off[s] = (unsigned)((wave * 32 + s * 8) * 64);
  }

  f32x4 accg[4][2] = {};
  f32x4 accu[4][2] = {};
  const int wm = wave >> 1, wn = wave & 1;

  unsigned a_off[4][2], bg_off[2][2], bu_off[2][2];
#pragma unroll
  for (int fr = 0; fr < 4; ++fr)
#pragma unroll
    for (int ks = 0; ks < 2; ++ks)
      a_off[fr][ks] = (wm * 64 + fr * 16 + (lane & 15)) * 64 + ks * 32 + (lane >> 4) * 8;
#pragma unroll
  for (int fn = 0; fn < 2; ++fn)
#pragma unroll
    for (int ks = 0; ks < 2; ++ks) {
      bg_off[fn][ks] = (wn * 32 + fn * 16 + (lane & 15)) * 64 + ks * 32 + (lane >> 4) * 8;
      bu_off[fn][ks] = bg_off[fn][ks] + 64 * 64;
    }

  for (int k0 = 0; k0 < H_DIM; k0 += 64) {
    __syncthreads();
    size_t kb = (size_t)k0 * 2;
#pragma unroll
    for (int s = 0; s < 4; ++s) {
      GLDS16((const char*)xh + a_byte[s] + kb, sAh + lds_off[s]);
      GLDS16((const char*)xl + a_byte[s] + kb, sAl + lds_off[s]);
      GLDS16((const char*)wh + b_byte[s] + kb, sBh + lds_off[s]);
      GLDS16((const char*)wl + b_byte[s] + kb, sBl + lds_off[s]);
    }
    __syncthreads();
#pragma unroll
    for (int ks = 0; ks < 2; ++ks) {
      half8 ah[4], al[4], bgh[2], bgl[2], buh[2], bul[2];
#pragma unroll
      for (int fr = 0; fr < 4; ++fr) {
        ah[fr] = *(const half8*)(sAh + a_off[fr][ks]);
        al[fr] = *(const half8*)(sAl + a_off[fr][ks]);
      }
#pragma unroll
      for (int fn = 0; fn < 2; ++fn) {
        bgh[fn] = *(const half8*)(sBh + bg_off[fn][ks]);
        bgl[fn] = *(const half8*)(sBl + bg_off[fn][ks]);
        buh[fn] = *(const half8*)(sBh + bu_off[fn][ks]);
        bul[fn] = *(const half8*)(sBl + bu_off[fn][ks]);
      }
#pragma unroll
      for (int fr = 0; fr < 4; ++fr)
#pragma unroll
        for (int fn = 0; fn < 2; ++fn) {
          accg[fr][fn] = __builtin_amdgcn_mfma_f32_16x16x32_f16(ah[fr], bgh[fn], accg[fr][fn], 0, 0, 0);
          accg[fr][fn] = __builtin_amdgcn_mfma_f32_16x16x32_f16(ah[fr], bgl[fn], accg[fr][fn], 0, 0, 0);
          accg[fr][fn] = __builtin_amdgcn_mfma_f32_16x16x32_f16(al[fr], bgh[fn], accg[fr][fn], 0, 0, 0);
          accu[fr][fn] = __builtin_amdgcn_mfma_f32_16x16x32_f16(ah[fr], buh[fn], accu[fr][fn], 0, 0, 0);
          accu[fr][fn] = __builtin_amdgcn_mfma_f32_16x16x32_f16(ah[fr], bul[fn], accu[fr][fn], 0, 0, 0);
          accu[fr][fn] = __builtin_amdgcn_mfma_f32_16x16x32_f16(al[fr], buh[fn], accu[fr][fn], 0, 0, 0);
        }
    }
  }

  __syncthreads();
  _Float16* sStage = sAh;  // reuse
#pragma unroll
  for (int fr = 0; fr < 4; ++fr)
#pragma unroll
    for (int fn = 0; fn < 2; ++fn) {
      float act[4], am[4];
#pragma unroll
      for (int i = 0; i < 4; ++i) {
        float g = accg[fr][fn][i], u = accu[fr][fn][i];
        float sg = 1.0f / (1.0f + expf(-g));
        float si = g * sg;
        act[i] = si * u;
        am[i] = fabsf(act[i]);
      }
#pragma unroll
      for (int m = 1; m < 16; m <<= 1)
#pragma unroll
        for (int i = 0; i < 4; ++i) am[i] = fmaxf(am[i], __shfl_xor(am[i], m, 64));
      int col = wn * 32 + fn * 16 + (lane & 15);
#pragma unroll
      for (int i = 0; i < 4; ++i) {
        float scale = am[i] > 0.0f ? am[i] / 6.0f : 1.0f;
        float qv = fp4_q(act[i], scale);
        int row = wm * 64 + fr * 16 + (lane >> 4) * 4 + i;
        sStage[row * 64 + col] = (_Float16)qv;
      }
    }
  __syncthreads();
#pragma unroll
  for (int s = 0; s < 4; ++s) {
    int idx2 = tid + s * 256;
    int r = idx2 >> 3, c = idx2 & 7;
    if (r < nvalid) {
      *(uint4*)(aq + ((size_t)(e * T_TOK + row0 + r) * I_DIM + n0 + c * 8)) =
          *(const uint4*)(sStage + r * 64 + c * 8);
    }
  }
}

// GEMM2: y[slot, h] = aq[slot,:]*wd[h,:] (1-pass f16), epilogue w_te-scaled
// atomic accumulate into out[token, h].
__launch_bounds__(256, 2)
__global__ void gemm2_kernel(const _Float16* __restrict__ aq, const _Float16* __restrict__ wdh,
                             const int* __restrict__ counts, const int* __restrict__ list,
                             const float* __restrict__ w_te, float* __restrict__ out) {
  __shared__ __align__(16) _Float16 sA[128 * 64];
  __shared__ __align__(16) _Float16 sB[128 * 64];
  __shared__ int   s_trow[128];
  __shared__ float s_wrow[128];

  const int e = blockIdx.z, tile = blockIdx.y;
  const int cnt = counts[e];
  const int row0 = tile * 128;
  if (row0 >= cnt) return;
  const int nvalid = min(128, cnt - row0);
  const int n1  = blockIdx.x * 128;
  const int tid = threadIdx.x;
  const int wave = tid >> 6, lane = tid & 63;

  if (tid < 128) {
    int r = (tid < nvalid) ? tid : 0;
    int t = list[e * T_TOK + row0 + r];
    s_trow[tid] = t;
    s_wrow[tid] = w_te[t * N_EXP + e];
  }

  size_t a_byte[4], b_byte[4];
  unsigned lds_off[4];
#pragma unroll
  for (int s = 0; s < 4; ++s) {
    int r = wave * 32 + s * 8 + (lane >> 3);
    int ra = (r < nvalid) ? r : 0;
    a_byte[s] = (((size_t)(e * T_TOK + row0 + ra)) * I_DIM + (size_t)((lane & 7) * 8)) * 2;
    b_byte[s] = (((size_t)(e * H_DIM + n1 + r)) * I_DIM + (size_t)((lane & 7) * 8)) * 2;
    lds_off[s] = (unsigned)((wave * 32 + s * 8) * 64);
  }

  f32x4 acc[4][4] = {};
  const int wm = wave >> 1, wn = wave & 1;
  unsigned a_off[4][2], b_off[4][2];
#pragma unroll
  for (int fr = 0; fr < 4; ++fr)
#pragma unroll
    for (int ks = 0; ks < 2; ++ks)
      a_off[fr][ks] = (wm * 64 + fr * 16 + (lane & 15)) * 64 + ks * 32 + (lane >> 4) * 8;
#pragma unroll
  for (int fn = 0; fn < 4; ++fn)
#pragma unroll
    for (int ks = 0; ks < 2; ++ks)
      b_off[fn][ks] = (wn * 64 + fn * 16 + (lane & 15)) * 64 + ks * 32 + (lane >> 4) * 8;

  for (int k0 = 0; k0 < I_DIM; k0 += 64) {
    __syncthreads();
    size_t kb = (size_t)k0 * 2;
#pragma unroll
    for (int s = 0; s < 4; ++s) {
      GLDS16((const char*)aq  + a_byte[s] + kb, sA + lds_off[s]);
      GLDS16((const char*)wdh + b_byte[s] + kb, sB + lds_off[s]);
    }
    __syncthreads();
#pragma unroll
    for (int ks = 0; ks < 2; ++ks) {
      half8 a[4], b[4];
#pragma unroll
      for (int fr = 0; fr < 4; ++fr) a[fr] = *(const half8*)(sA + a_off[fr][ks]);
#pragma unroll
      for (int fn = 0; fn < 4; ++fn) b[fn] = *(const half8*)(sB + b_off[fn][ks]);
#pragma unroll
      for (int fr = 0; fr < 4; ++fr)
#pragma unroll
        for (int fn = 0; fn < 4; ++fn)
          acc[fr][fn] = __builtin_amdgcn_mfma_f32_16x16x32_f16(a[fr], b[fn], acc[fr][fn], 0, 0, 0);
    }
  }

#pragma unroll
  for (int fr = 0; fr < 4; ++fr) {
    int rb = wm * 64 + fr * 16 + (lane >> 4) * 4;
#pragma unroll
    for (int i = 0; i < 4; ++i) {
      int row = rb + i;
      if (row < nvalid) {
        int t = s_trow[row];
        float w = s_wrow[row];
#pragma unroll
        for (int fn = 0; fn < 4; ++fn) {
          int col = n1 + wn * 64 + fn * 16 + (lane & 15);
          unsafeAtomicAdd(&out[(size_t)t * H_DIM + col], w * acc[fr][fn][i]);
        }
      }
    }
  }
}

extern "C" void kernel_launch(void* const* d_in, const int* in_sizes, int n_in,
                              void* d_out, int out_size, void* d_ws, size_t ws_size,
                              hipStream_t stream) {
  const float* hs  = (const float*)d_in[0];
  const int*   tki = (const int*)d_in[1];
  const float* tkw = (const float*)d_in[2];
  const float* wgu = (const float*)d_in[3];
  const float* wd  = (const float*)d_in[4];
  float* out = (float*)d_out;

  char* ws = (char*)d_ws;
  size_t off = 0;
  auto alloc = [&](size_t bytes) -> void* {
    void* p = ws + off;
    off += bytes;
    off = (off + 255) & ~(size_t)255;
    return p;
  };
  int*      counts = (int*)alloc(N_EXP * 4);
  float*    w_te   = (float*)alloc((size_t)T_TOK * N_EXP * 4);
  int*      list   = (int*)alloc((size_t)N_EXP * T_TOK * 4);
  _Float16* xh     = (_Float16*)alloc((size_t)T_TOK * H_DIM * 2);
  _Float16* xl     = (_Float16*)alloc((size_t)T_TOK * H_DIM * 2);
  _Float16* wguh   = (_Float16*)alloc((size_t)N_EXP * 2 * I_DIM * H_DIM * 2);
  _Float16* wgul   = (_Float16*)alloc((size_t)N_EXP * 2 * I_DIM * H_DIM * 2);
  _Float16* wdh    = (_Float16*)alloc((size_t)N_EXP * H_DIM * I_DIM * 2);
  _Float16* aqb    = (_Float16*)alloc((size_t)N_EXP * T_TOK * I_DIM * 2);
  if (off > ws_size) return;  // workspace too small: bail (diagnosable as incorrect)

  zero_kernel<<<dim3(4096), dim3(256), 0, stream>>>(out, counts);
  router_kernel<<<dim3(8), dim3(256), 0, stream>>>(tki, tkw, w_te, counts, list);
  quant_kernel<<<dim3(4096), dim3(256), 0, stream>>>(hs, xh, xl, T_TOK * H_DIM / 4);
  quant_kernel<<<dim3(49152), dim3(256), 0, stream>>>(wgu, wguh, wgul, N_EXP * 2 * I_DIM * H_DIM / 4);
  quant_kernel<<<dim3(24576), dim3(256), 0, stream>>>(wd, wdh, (_Float16*)nullptr, N_EXP * H_DIM * I_DIM / 4);
  gemm1_kernel<<<dim3(I_DIM / 64, 16, N_EXP), dim3(256), 0, stream>>>(xh, xl, wguh, wgul, counts, list, aqb);
  gemm2_kernel<<<dim3(H_DIM / 128, 16, N_EXP), dim3(256), 0, stream>>>(aqb, wdh, counts, list, w_te, out);
}

// Round 2
// 822.916 us; speedup vs baseline: 1.0206x; 1.0206x over previous
//
#include <hip/hip_runtime.h>
#include <hip/hip_fp16.h>
#include <cstdint>

#define T_TOK 2048
#define H_DIM 2048
#define I_DIM 768
#define N_EXP 16
#define TOPK  8

typedef _Float16 half8  __attribute__((ext_vector_type(8)));
typedef _Float16 half4v __attribute__((ext_vector_type(4)));
typedef float    f32x4  __attribute__((ext_vector_type(4)));

#define GLDS16(g, l)                                                        \
  __builtin_amdgcn_global_load_lds(                                         \
      (const __attribute__((address_space(1))) unsigned int*)(g),           \
      (__attribute__((address_space(3))) unsigned int*)(l), 16, 0, 0)

// Bit-exact replication of the reference fp4 fake-quant (ties round UP like
// jnp.digitize(right=False)): v = x/scale in f32, snap |v| to e2m1 grid.
__device__ __forceinline__ float fp4_q(float x, float scale) {
  float v = x / scale;
  float a = fabsf(v);
  float q;
  if      (a < 0.25f) q = 0.0f;
  else if (a < 0.75f) q = 0.5f;
  else if (a < 1.25f) q = 1.0f;
  else if (a < 1.75f) q = 1.5f;
  else if (a < 2.5f)  q = 2.0f;
  else if (a < 3.5f)  q = 3.0f;
  else if (a < 5.0f)  q = 4.0f;
  else                q = 6.0f;
  return copysignf(q, v) * scale;
}

// LDS chunk swizzle: 64B rows = 4 x 16B chunks; chunk c of row r holds global
// chunk c ^ m(r). m spreads 8 consecutive rows across 8 distinct bank slots
// (2-way aliasing over 16 rows = free per m136). Involution: same XOR on the
// global-source address (linear global_load_lds dest) and on the ds_read addr.
__device__ __forceinline__ int swz_m(int r) { return (r & 3) ^ ((r >> 2) & 1); }

__global__ void zero_kernel(float* __restrict__ out, int* __restrict__ counts) {
  int gid = blockIdx.x * 256 + threadIdx.x;
  ((f32x4*)out)[gid] = (f32x4){0.f, 0.f, 0.f, 0.f};
  if (gid < N_EXP) counts[gid] = 0;
}

__global__ void router_kernel(const int* __restrict__ idx, const float* __restrict__ wts,
                              float* __restrict__ w_te, int* __restrict__ counts,
                              int* __restrict__ list) {
  int t = blockIdx.x * 256 + threadIdx.x;
  if (t >= T_TOK) return;
  int   id[TOPK];
  float w[TOPK];
#pragma unroll
  for (int k = 0; k < TOPK; ++k) { id[k] = idx[t * TOPK + k]; w[k] = wts[t * TOPK + k]; }
#pragma unroll
  for (int e = 0; e < N_EXP; ++e) {
    float acc = 0.f;
#pragma unroll
    for (int k = 0; k < TOPK; ++k) acc += (id[k] == e) ? w[k] : 0.0f;
    w_te[t * N_EXP + e] = acc;
    if (acc != 0.0f) {
      int pos = atomicAdd(&counts[e], 1);
      list[e * T_TOK + pos] = t;
    }
  }
}

// One float4 per lane; per-16-element quant block = 4 consecutive lanes.
// Outputs f16 hi (and optional f16 lo residual) for error-free split GEMM.
__global__ void quant_kernel(const float* __restrict__ src, _Float16* __restrict__ dh,
                             _Float16* __restrict__ dl, int n4) {
  int gid = blockIdx.x * 256 + threadIdx.x;
  if (gid >= n4) return;
  f32x4 x = ((const f32x4*)src)[gid];
  float am = fmaxf(fmaxf(fabsf(x[0]), fabsf(x[1])), fmaxf(fabsf(x[2]), fabsf(x[3])));
  am = fmaxf(am, __shfl_xor(am, 1, 64));
  am = fmaxf(am, __shfl_xor(am, 2, 64));
  float scale = am > 0.0f ? am / 6.0f : 1.0f;
  half4v hv, lv;
#pragma unroll
  for (int j = 0; j < 4; ++j) {
    float xq = fp4_q(x[j], scale);
    _Float16 h = (_Float16)xq;
    hv[j] = h;
    lv[j] = (_Float16)(xq - (float)h);
  }
  ((half4v*)dh)[gid] = hv;
  if (dl) ((half4v*)dl)[gid] = lv;
}

// GEMM1: per-expert gathered tokens, 128 tokens x (64 gate + 64 up cols),
// BK=32, double-buffered LDS, 2-phase pipeline (STAGE next before compute cur,
// one barrier per K-step), T2 XOR-swizzled LDS, XCD-swizzled grid (tile
// fastest for B-panel L2 reuse). 3-pass f16 split: Xh*Wh + Xh*Wl + Xl*Wh.
// Epilogue: silu(gate)*up -> bit-exact fp4 fake-quant along INTER -> aq (f16).
__launch_bounds__(256, 2)
__global__ void gemm1_kernel(const _Float16* __restrict__ xh, const _Float16* __restrict__ xl,
                             const _Float16* __restrict__ wh, const _Float16* __restrict__ wl,
                             const int* __restrict__ counts, const int* __restrict__ list,
                             _Float16* __restrict__ aq) {
  __shared__ __align__(16) _Float16 smem[2][4][128 * 32];  // [buf][Ah,Al,Bh,Bl] 64 KB
  __shared__ int s_tok[128];

  // bijective XCD swizzle (m204, 3072 % 8 == 0), token-tile fastest
  const int orig = blockIdx.x;
  const int swz  = (orig & 7) * (3072 / 8) + (orig >> 3);
  const int tile = swz & 15;
  const int n0i  = (swz >> 4) % 12;
  const int e    = swz / 192;

  const int cnt  = counts[e];
  const int row0 = tile * 128;
  if (row0 >= cnt) return;
  const int nvalid = min(128, cnt - row0);
  const int n0  = n0i * 64;
  const int tid = threadIdx.x;
  const int wave = tid >> 6, lane = tid & 63;

  if (tid < 128) {
    int r = (tid < nvalid) ? tid : 0;
    s_tok[tid] = list[e * T_TOK + row0 + r];
  }
  __syncthreads();

  // staging descriptors: 512 16B chunks per tensor; thread owns q=tid, tid+256
  size_t aG[2], bG[2];
  unsigned ldsOff[2];
#pragma unroll
  for (int p = 0; p < 2; ++p) {
    int q = tid + p * 256;
    int r = q >> 2, c = q & 3;
    int sc = c ^ swz_m(r);
    ldsOff[p] = (unsigned)q * 8;  // f16 elements
    int tok = s_tok[r];
    aG[p] = ((size_t)tok * H_DIM) * 2 + (size_t)(sc * 16);
    int grow = (r < 64) ? (e * 2 * I_DIM + n0 + r)
                        : (e * 2 * I_DIM + I_DIM + n0 + (r - 64));
    bG[p] = ((size_t)grow * H_DIM) * 2 + (size_t)(sc * 16);
  }

  const int wm = wave >> 1, wn = wave & 1;
  const int kc = lane >> 4;
  unsigned aRd[4], bgRd[2], buRd[2];
#pragma unroll
  for (int fr = 0; fr < 4; ++fr) {
    int R = wm * 64 + fr * 16 + (lane & 15);
    aRd[fr] = (unsigned)(R * 32 + (kc ^ swz_m(R)) * 8);
  }
#pragma unroll
  for (int fn = 0; fn < 2; ++fn) {
    int R = wn * 32 + fn * 16 + (lane & 15);
    bgRd[fn] = (unsigned)(R * 32 + (kc ^ swz_m(R)) * 8);
    int R2 = R + 64;
    buRd[fn] = (unsigned)(R2 * 32 + (kc ^ swz_m(R2)) * 8);
  }

  f32x4 accg[4][2] = {};
  f32x4 accu[4][2] = {};

#define STAGE1(buf, k0)                                                       \
  do {                                                                        \
    size_t kb = (size_t)(k0) * 2;                                             \
    _Pragma("unroll") for (int p = 0; p < 2; ++p) {                           \
      GLDS16((const char*)xh + aG[p] + kb, &smem[buf][0][0] + ldsOff[p]);     \
      GLDS16((const char*)xl + aG[p] + kb, &smem[buf][1][0] + ldsOff[p]);     \
      GLDS16((const char*)wh + bG[p] + kb, &smem[buf][2][0] + ldsOff[p]);     \
      GLDS16((const char*)wl + bG[p] + kb, &smem[buf][3][0] + ldsOff[p]);     \
    }                                                                         \
  } while (0)

  STAGE1(0, 0);
  __syncthreads();  // drains prologue stage (vmcnt0 + barrier)
  const int NT = H_DIM / 32;
  for (int t = 0; t < NT; ++t) {
    const int cur = t & 1;
    if (t + 1 < NT) STAGE1(cur ^ 1, (t + 1) * 32);  // issue-early: hides under MFMA
    const _Float16* sAh = &smem[cur][0][0];
    const _Float16* sAl = &smem[cur][1][0];
    const _Float16* sBh = &smem[cur][2][0];
    const _Float16* sBl = &smem[cur][3][0];
    half8 ah[4], al[4], bgh[2], bgl[2], buh[2], bul[2];
#pragma unroll
    for (int fr = 0; fr < 4; ++fr) {
      ah[fr] = *(const half8*)(sAh + aRd[fr]);
      al[fr] = *(const half8*)(sAl + aRd[fr]);
    }
#pragma unroll
    for (int fn = 0; fn < 2; ++fn) {
      bgh[fn] = *(const half8*)(sBh + bgRd[fn]);
      bgl[fn] = *(const half8*)(sBl + bgRd[fn]);
      buh[fn] = *(const half8*)(sBh + buRd[fn]);
      bul[fn] = *(const half8*)(sBl + buRd[fn]);
    }
#pragma unroll
    for (int fr = 0; fr < 4; ++fr)
#pragma unroll
      for (int fn = 0; fn < 2; ++fn) {
        accg[fr][fn] = __builtin_amdgcn_mfma_f32_16x16x32_f16(ah[fr], bgh[fn], accg[fr][fn], 0, 0, 0);
        accg[fr][fn] = __builtin_amdgcn_mfma_f32_16x16x32_f16(ah[fr], bgl[fn], accg[fr][fn], 0, 0, 0);
        accg[fr][fn] = __builtin_amdgcn_mfma_f32_16x16x32_f16(al[fr], bgh[fn], accg[fr][fn], 0, 0, 0);
        accu[fr][fn] = __builtin_amdgcn_mfma_f32_16x16x32_f16(ah[fr], buh[fn], accu[fr][fn], 0, 0, 0);
        accu[fr][fn] = __builtin_amdgcn_mfma_f32_16x16x32_f16(ah[fr], bul[fn], accu[fr][fn], 0, 0, 0);
        accu[fr][fn] = __builtin_amdgcn_mfma_f32_16x16x32_f16(al[fr], buh[fn], accu[fr][fn], 0, 0, 0);
      }
    __syncthreads();  // vmcnt(0)+barrier: next-tile loads landed, cur reads done
  }
#undef STAGE1

  // epilogue: act quant + store aq; reuse smem[0][0..1] as [128][64] f16 stage
  _Float16* sStage = &smem[0][0][0];
#pragma unroll
  for (int fr = 0; fr < 4; ++fr)
#pragma unroll
    for (int fn = 0; fn < 2; ++fn) {
      float act[4], am[4];
#pragma unroll
      for (int i = 0; i < 4; ++i) {
        float g = accg[fr][fn][i], u = accu[fr][fn][i];
        float sg = 1.0f / (1.0f + expf(-g));
        act[i] = g * sg * u;
        am[i] = fabsf(act[i]);
      }
#pragma unroll
      for (int m = 1; m < 16; m <<= 1)
#pragma unroll
        for (int i = 0; i < 4; ++i) am[i] = fmaxf(am[i], __shfl_xor(am[i], m, 64));
      int col = wn * 32 + fn * 16 + (lane & 15);
#pragma unroll
      for (int i = 0; i < 4; ++i) {
        float scale = am[i] > 0.0f ? am[i] / 6.0f : 1.0f;
        float qv = fp4_q(act[i], scale);
        int row = wm * 64 + fr * 16 + (lane >> 4) * 4 + i;
        sStage[row * 64 + col] = (_Float16)qv;
      }
    }
  __syncthreads();
#pragma unroll
  for (int s = 0; s < 4; ++s) {
    int idx2 = tid + s * 256;
    int r = idx2 >> 3, c = idx2 & 7;
    if (r < nvalid) {
      *(uint4*)(aq + ((size_t)(e * T_TOK + row0 + r) * I_DIM + n0 + c * 8)) =
          *(const uint4*)(sStage + r * 64 + c * 8);
    }
  }
}

// GEMM2: y[slot, h] = aq[slot,:]*wd[h,:] (1-pass f16), BK=32 dbuf 2-phase,
// swizzled LDS + grid; epilogue w_te-scaled atomic accumulate into out.
__launch_bounds__(256, 3)
__global__ void gemm2_kernel(const _Float16* __restrict__ aq, const _Float16* __restrict__ wdh,
                             const int* __restrict__ counts, const int* __restrict__ list,
                             const float* __restrict__ w_te, float* __restrict__ out) {
  __shared__ __align__(16) _Float16 smem[2][2][128 * 32];  // [buf][A,B] 32 KB
  __shared__ int   s_trow[128];
  __shared__ float s_wrow[128];

  const int orig = blockIdx.x;
  const int swz  = (orig & 7) * (4096 / 8) + (orig >> 3);
  const int tile = swz & 15;
  const int n1i  = (swz >> 4) & 15;
  const int e    = swz >> 8;

  const int cnt  = counts[e];
  const int row0 = tile * 128;
  if (row0 >= cnt) return;
  const int nvalid = min(128, cnt - row0);
  const int n1  = n1i * 128;
  const int tid = threadIdx.x;
  const int wave = tid >> 6, lane = tid & 63;

  if (tid < 128) {
    int r = (tid < nvalid) ? tid : 0;
    int t = list[e * T_TOK + row0 + r];
    s_trow[tid] = t;
    s_wrow[tid] = w_te[t * N_EXP + e];
  }

  size_t aG[2], bG[2];
  unsigned ldsOff[2];
#pragma unroll
  for (int p = 0; p < 2; ++p) {
    int q = tid + p * 256;
    int r = q >> 2, c = q & 3;
    int sc = c ^ swz_m(r);
    ldsOff[p] = (unsigned)q * 8;
    int ra = (r < nvalid) ? r : 0;
    aG[p] = ((size_t)(e * T_TOK + row0 + ra) * I_DIM) * 2 + (size_t)(sc * 16);
    bG[p] = ((size_t)(e * H_DIM + n1 + r) * I_DIM) * 2 + (size_t)(sc * 16);
  }

  const int wm = wave >> 1, wn = wave & 1;
  const int kc = lane >> 4;
  unsigned aRd[4], bRd[4];
#pragma unroll
  for (int fr = 0; fr < 4; ++fr) {
    int R = wm * 64 + fr * 16 + (lane & 15);
    aRd[fr] = (unsigned)(R * 32 + (kc ^ swz_m(R)) * 8);
  }
#pragma unroll
  for (int fn = 0; fn < 4; ++fn) {
    int R = wn * 64 + fn * 16 + (lane & 15);
    bRd[fn] = (unsigned)(R * 32 + (kc ^ swz_m(R)) * 8);
  }

  f32x4 acc[4][4] = {};

#define STAGE2(buf, k0)                                                       \
  do {                                                                        \
    size_t kb = (size_t)(k0) * 2;                                             \
    _Pragma("unroll") for (int p = 0; p < 2; ++p) {                           \
      GLDS16((const char*)aq  + aG[p] + kb, &smem[buf][0][0] + ldsOff[p]);    \
      GLDS16((const char*)wdh + bG[p] + kb, &smem[buf][1][0] + ldsOff[p]);    \
    }                                                                         \
  } while (0)

  STAGE2(0, 0);
  __syncthreads();
  const int NT = I_DIM / 32;
  for (int t = 0; t < NT; ++t) {
    const int cur = t & 1;
    if (t + 1 < NT) STAGE2(cur ^ 1, (t + 1) * 32);
    const _Float16* sA = &smem[cur][0][0];
    const _Float16* sB = &smem[cur][1][0];
    half8 a[4], b[4];
#pragma unroll
    for (int fr = 0; fr < 4; ++fr) a[fr] = *(const half8*)(sA + aRd[fr]);
#pragma unroll
    for (int fn = 0; fn < 4; ++fn) b[fn] = *(const half8*)(sB + bRd[fn]);
#pragma unroll
    for (int fr = 0; fr < 4; ++fr)
#pragma unroll
      for (int fn = 0; fn < 4; ++fn)
        acc[fr][fn] = __builtin_amdgcn_mfma_f32_16x16x32_f16(a[fr], b[fn], acc[fr][fn], 0, 0, 0);
    __syncthreads();
  }
#undef STAGE2

#pragma unroll
  for (int fr = 0; fr < 4; ++fr) {
    int rb = wm * 64 + fr * 16 + (lane >> 4) * 4;
#pragma unroll
    for (int i = 0; i < 4; ++i) {
      int row = rb + i;
      if (row < nvalid) {
        int t = s_trow[row];
        float w = s_wrow[row];
#pragma unroll
        for (int fn = 0; fn < 4; ++fn) {
          int col = n1 + wn * 64 + fn * 16 + (lane & 15);
          unsafeAtomicAdd(&out[(size_t)t * H_DIM + col], w * acc[fr][fn][i]);
        }
      }
    }
  }
}

extern "C" void kernel_launch(void* const* d_in, const int* in_sizes, int n_in,
                              void* d_out, int out_size, void* d_ws, size_t ws_size,
                              hipStream_t stream) {
  const float* hs  = (const float*)d_in[0];
  const int*   tki = (const int*)d_in[1];
  const float* tkw = (const float*)d_in[2];
  const float* wgu = (const float*)d_in[3];
  const float* wd  = (const float*)d_in[4];
  float* out = (float*)d_out;

  char* ws = (char*)d_ws;
  size_t off = 0;
  auto alloc = [&](size_t bytes) -> void* {
    void* p = ws + off;
    off += bytes;
    off = (off + 255) & ~(size_t)255;
    return p;
  };
  int*      counts = (int*)alloc(N_EXP * 4);
  float*    w_te   = (float*)alloc((size_t)T_TOK * N_EXP * 4);
  int*      list   = (int*)alloc((size_t)N_EXP * T_TOK * 4);
  _Float16* xh     = (_Float16*)alloc((size_t)T_TOK * H_DIM * 2);
  _Float16* xl     = (_Float16*)alloc((size_t)T_TOK * H_DIM * 2);
  _Float16* wguh   = (_Float16*)alloc((size_t)N_EXP * 2 * I_DIM * H_DIM * 2);
  _Float16* wgul   = (_Float16*)alloc((size_t)N_EXP * 2 * I_DIM * H_DIM * 2);
  _Float16* wdh    = (_Float16*)alloc((size_t)N_EXP * H_DIM * I_DIM * 2);
  _Float16* aqb    = (_Float16*)alloc((size_t)N_EXP * T_TOK * I_DIM * 2);
  if (off > ws_size) return;

  zero_kernel<<<dim3(4096), dim3(256), 0, stream>>>(out, counts);
  router_kernel<<<dim3(8), dim3(256), 0, stream>>>(tki, tkw, w_te, counts, list);
  quant_kernel<<<dim3(4096), dim3(256), 0, stream>>>(hs, xh, xl, T_TOK * H_DIM / 4);
  quant_kernel<<<dim3(49152), dim3(256), 0, stream>>>(wgu, wguh, wgul, N_EXP * 2 * I_DIM * H_DIM / 4);
  quant_kernel<<<dim3(24576), dim3(256), 0, stream>>>(wd, wdh, (_Float16*)nullptr, N_EXP * H_DIM * I_DIM / 4);
  gemm1_kernel<<<dim3(3072), dim3(256), 0, stream>>>(xh, xl, wguh, wgul, counts, list, aqb);
  gemm2_kernel<<<dim3(4096), dim3(256), 0, stream>>>(aqb, wdh, counts, list, w_te, out);
}

// Round 6
// 777.196 us; speedup vs baseline: 1.0806x; 1.0588x over previous
//
#include <hip/hip_runtime.h>
#include <hip/hip_fp16.h>
#include <cstdint>

#define T_TOK 2048
#define H_DIM 2048
#define I_DIM 768
#define N_EXP 16
#define TOPK  8

typedef _Float16 half8  __attribute__((ext_vector_type(8)));
typedef _Float16 half4v __attribute__((ext_vector_type(4)));
typedef float    f32x4  __attribute__((ext_vector_type(4)));

#define GLDS16(g, l)                                                        \
  __builtin_amdgcn_global_load_lds(                                         \
      (const __attribute__((address_space(1))) unsigned int*)(g),           \
      (__attribute__((address_space(3))) unsigned int*)(l), 16, 0, 0)

// Bit-exact replication of the reference fp4 fake-quant (ties round UP like
// jnp.digitize(right=False)): v = x/scale in f32, snap |v| to e2m1 grid.
__device__ __forceinline__ float fp4_q(float x, float scale) {
  float v = x / scale;
  float a = fabsf(v);
  float q;
  if      (a < 0.25f) q = 0.0f;
  else if (a < 0.75f) q = 0.5f;
  else if (a < 1.25f) q = 1.0f;
  else if (a < 1.75f) q = 1.5f;
  else if (a < 2.5f)  q = 2.0f;
  else if (a < 3.5f)  q = 3.0f;
  else if (a < 5.0f)  q = 4.0f;
  else                q = 6.0f;
  return copysignf(q, v) * scale;
}

__global__ void zero_kernel(float* __restrict__ out, int* __restrict__ counts) {
  int gid = blockIdx.x * 256 + threadIdx.x;
  ((f32x4*)out)[gid] = (f32x4){0.f, 0.f, 0.f, 0.f};
  if (gid < N_EXP) counts[gid] = 0;
}

__global__ void router_kernel(const int* __restrict__ idx, const float* __restrict__ wts,
                              float* __restrict__ w_te, int* __restrict__ counts,
                              int* __restrict__ list) {
  int t = blockIdx.x * 256 + threadIdx.x;
  if (t >= T_TOK) return;
  int   id[TOPK];
  float w[TOPK];
#pragma unroll
  for (int k = 0; k < TOPK; ++k) { id[k] = idx[t * TOPK + k]; w[k] = wts[t * TOPK + k]; }
#pragma unroll
  for (int e = 0; e < N_EXP; ++e) {
    float acc = 0.f;
#pragma unroll
    for (int k = 0; k < TOPK; ++k) acc += (id[k] == e) ? w[k] : 0.0f;
    w_te[t * N_EXP + e] = acc;
    if (acc != 0.0f) {
      int pos = atomicAdd(&counts[e], 1);
      list[e * T_TOK + pos] = t;
    }
  }
}

// One float4 per lane; per-16-element quant block = 4 consecutive lanes.
// Outputs f16 hi (and optional f16 lo residual) for error-free split GEMM.
__global__ void quant_kernel(const float* __restrict__ src, _Float16* __restrict__ dh,
                             _Float16* __restrict__ dl, int n4) {
  int gid = blockIdx.x * 256 + threadIdx.x;
  if (gid >= n4) return;
  f32x4 x = ((const f32x4*)src)[gid];
  float am = fmaxf(fmaxf(fabsf(x[0]), fabsf(x[1])), fmaxf(fabsf(x[2]), fabsf(x[3])));
  am = fmaxf(am, __shfl_xor(am, 1, 64));
  am = fmaxf(am, __shfl_xor(am, 2, 64));
  float scale = am > 0.0f ? am / 6.0f : 1.0f;
  half4v hv, lv;
#pragma unroll
  for (int j = 0; j < 4; ++j) {
    float xq = fp4_q(x[j], scale);
    _Float16 h = (_Float16)xq;
    hv[j] = h;
    lv[j] = (_Float16)(xq - (float)h);
  }
  ((half4v*)dh)[gid] = hv;
  if (dl) ((half4v*)dl)[gid] = lv;
}

// GEMM1 v5: exact 3-pass f16 split (Xh*Wh + Xh*Wl + Xl*Wh), 128 tok x 64
// aq-cols (B = 64 gate + 64 up rows). m97-style SINGLE-buffer BK=64
// (4 tensors x 16KB = 64KB, 2 blocks/CU overlap staging vs compute), 8-chunk
// XOR swizzle on 128B rows (bank = f(chunk) only -> b128 reads conflict-free),
// XCD-swizzled grid. Epilogue: silu*up -> bit-exact fp4 quant -> aq (f16).
__launch_bounds__(256, 2)
__global__ void gemm1_kernel(const _Float16* __restrict__ xh, const _Float16* __restrict__ xl,
                             const _Float16* __restrict__ wh, const _Float16* __restrict__ wl,
                             const int* __restrict__ counts, const int* __restrict__ list,
                             _Float16* __restrict__ aq) {
  __shared__ __align__(16) _Float16 sAh[128 * 64];  // 16 KB each
  __shared__ __align__(16) _Float16 sAl[128 * 64];
  __shared__ __align__(16) _Float16 sBh[128 * 64];  // rows 0-63 gate, 64-127 up
  __shared__ __align__(16) _Float16 sBl[128 * 64];
  __shared__ int s_tok[128];

  // bijective XCD swizzle (3072 % 8 == 0), token-tile fastest for B L2 reuse
  const int orig = blockIdx.x;
  const int swz  = (orig & 7) * (3072 / 8) + (orig >> 3);
  const int tile = swz & 15;
  const int n0i  = (swz >> 4) % 12;
  const int e    = swz / 192;

  const int cnt  = counts[e];
  const int row0 = tile * 128;
  if (row0 >= cnt) return;
  const int nvalid = min(128, cnt - row0);
  const int n0  = n0i * 64;
  const int tid = threadIdx.x;
  const int wave = tid >> 6, lane = tid & 63;

  if (tid < 128) {
    int r = (tid < nvalid) ? tid : 0;
    s_tok[tid] = list[e * T_TOK + row0 + r];
  }
  __syncthreads();

  // staging: each tensor = 128 rows x 8 x 16B chunks = 1024 chunks; 4/thread.
  // LDS linear (GLDS dest), global source pre-swizzled: chunk c <- global c^(r&7)
  size_t aG[4], bG[4];
  unsigned ldsOff[4];
#pragma unroll
  for (int p = 0; p < 4; ++p) {
    int q = tid + p * 256;
    int r = q >> 3, c = q & 7;
    int sc = c ^ (r & 7);
    ldsOff[p] = (unsigned)q * 8;  // f16 elements (16B chunks)
    aG[p] = ((size_t)s_tok[r] * H_DIM) * 2 + (size_t)(sc * 16);
    int grow = (r < 64) ? (e * 2 * I_DIM + n0 + r)
                        : (e * 2 * I_DIM + I_DIM + n0 + (r - 64));
    bG[p] = ((size_t)grow * H_DIM) * 2 + (size_t)(sc * 16);
  }

  // read offsets: MFMA A/B frag = 16B at (row R, k-chunk g = ks*4 + (lane>>4));
  // LDS chunk = g ^ (R&7). Per-instruction bank load = 8/bank = b128 minimum.
  const int wm = wave >> 1, wn = wave & 1;
  const int kc = lane >> 4;
  unsigned aRd[4][2], bgRd[2][2], buRd[2][2];
#pragma unroll
  for (int fr = 0; fr < 4; ++fr) {
    int R = wm * 64 + fr * 16 + (lane & 15);
#pragma unroll
    for (int ks = 0; ks < 2; ++ks)
      aRd[fr][ks] = (unsigned)(R * 64 + (((ks * 4 + kc) ^ (R & 7)) * 8));
  }
#pragma unroll
  for (int fn = 0; fn < 2; ++fn) {
    int Rg = wn * 32 + fn * 16 + (lane & 15);
    int Ru = Rg + 64;
#pragma unroll
    for (int ks = 0; ks < 2; ++ks) {
      bgRd[fn][ks] = (unsigned)(Rg * 64 + (((ks * 4 + kc) ^ (Rg & 7)) * 8));
      buRd[fn][ks] = (unsigned)(Ru * 64 + (((ks * 4 + kc) ^ (Ru & 7)) * 8));
    }
  }

  f32x4 accg[4][2] = {};
  f32x4 accu[4][2] = {};

  const int NT = H_DIM / 64;
  for (int t = 0; t < NT; ++t) {
    __syncthreads();  // all waves done reading the buffer before overwrite
    {
      size_t kb = (size_t)t * 128;  // 64 f16 = 128 bytes per K-step
#pragma unroll
      for (int p = 0; p < 4; ++p) {
        GLDS16((const char*)xh + aG[p] + kb, sAh + ldsOff[p]);
        GLDS16((const char*)xl + aG[p] + kb, sAl + ldsOff[p]);
        GLDS16((const char*)wh + bG[p] + kb, sBh + ldsOff[p]);
        GLDS16((const char*)wl + bG[p] + kb, sBl + ldsOff[p]);
      }
    }
    __syncthreads();  // vmcnt0+lgkm0+barrier: staged tile visible to all
#pragma unroll
    for (int ks = 0; ks < 2; ++ks) {
      half8 ah[4], al[4], bgh[2], bgl[2], buh[2], bul[2];
#pragma unroll
      for (int fr = 0; fr < 4; ++fr) {
        ah[fr] = *(const half8*)(sAh + aRd[fr][ks]);
        al[fr] = *(const half8*)(sAl + aRd[fr][ks]);
      }
#pragma unroll
      for (int fn = 0; fn < 2; ++fn) {
        bgh[fn] = *(const half8*)(sBh + bgRd[fn][ks]);
        bgl[fn] = *(const half8*)(sBl + bgRd[fn][ks]);
        buh[fn] = *(const half8*)(sBh + buRd[fn][ks]);
        bul[fn] = *(const half8*)(sBl + buRd[fn][ks]);
      }
#pragma unroll
      for (int fr = 0; fr < 4; ++fr)
#pragma unroll
        for (int fn = 0; fn < 2; ++fn) {
          accg[fr][fn] = __builtin_amdgcn_mfma_f32_16x16x32_f16(ah[fr], bgh[fn], accg[fr][fn], 0, 0, 0);
          accg[fr][fn] = __builtin_amdgcn_mfma_f32_16x16x32_f16(ah[fr], bgl[fn], accg[fr][fn], 0, 0, 0);
          accg[fr][fn] = __builtin_amdgcn_mfma_f32_16x16x32_f16(al[fr], bgh[fn], accg[fr][fn], 0, 0, 0);
          accu[fr][fn] = __builtin_amdgcn_mfma_f32_16x16x32_f16(ah[fr], buh[fn], accu[fr][fn], 0, 0, 0);
          accu[fr][fn] = __builtin_amdgcn_mfma_f32_16x16x32_f16(ah[fr], bul[fn], accu[fr][fn], 0, 0, 0);
          accu[fr][fn] = __builtin_amdgcn_mfma_f32_16x16x32_f16(al[fr], buh[fn], accu[fr][fn], 0, 0, 0);
        }
    }
  }

  __syncthreads();
  // epilogue: act quant + store aq; reuse sAh as [128][64] f16 stage
  _Float16* sStage = sAh;
#pragma unroll
  for (int fr = 0; fr < 4; ++fr)
#pragma unroll
    for (int fn = 0; fn < 2; ++fn) {
      float act[4], am[4];
#pragma unroll
      for (int i = 0; i < 4; ++i) {
        float g = accg[fr][fn][i], u = accu[fr][fn][i];
        float sg = 1.0f / (1.0f + expf(-g));
        act[i] = g * sg * u;
        am[i] = fabsf(act[i]);
      }
#pragma unroll
      for (int m = 1; m < 16; m <<= 1)
#pragma unroll
        for (int i = 0; i < 4; ++i) am[i] = fmaxf(am[i], __shfl_xor(am[i], m, 64));
      int col = wn * 32 + fn * 16 + (lane & 15);
#pragma unroll
      for (int i = 0; i < 4; ++i) {
        float scale = am[i] > 0.0f ? am[i] / 6.0f : 1.0f;
        float qv = fp4_q(act[i], scale);
        int row = wm * 64 + fr * 16 + (lane >> 4) * 4 + i;
        sStage[row * 64 + col] = (_Float16)qv;
      }
    }
  __syncthreads();
#pragma unroll
  for (int s = 0; s < 4; ++s) {
    int idx2 = tid + s * 256;
    int r = idx2 >> 3, c = idx2 & 7;
    if (r < nvalid) {
      *(uint4*)(aq + ((size_t)(e * T_TOK + row0 + r) * I_DIM + n0 + c * 8)) =
          *(const uint4*)(sStage + r * 64 + c * 8);
    }
  }
}

// GEMM2: y[slot, h] = aq[slot,:]*wd[h,:] (1-pass f16), BK=32 dbuf 2-phase,
// swizzled LDS + grid; epilogue w_te-scaled atomic accumulate into out.
__device__ __forceinline__ int swz_m(int r) { return (r & 3) ^ ((r >> 2) & 1); }

__launch_bounds__(256, 3)
__global__ void gemm2_kernel(const _Float16* __restrict__ aq, const _Float16* __restrict__ wdh,
                             const int* __restrict__ counts, const int* __restrict__ list,
                             const float* __restrict__ w_te, float* __restrict__ out) {
  __shared__ __align__(16) _Float16 smem[2][2][128 * 32];  // [buf][A,B] 32 KB
  __shared__ int   s_trow[128];
  __shared__ float s_wrow[128];

  const int orig = blockIdx.x;
  const int swz  = (orig & 7) * (4096 / 8) + (orig >> 3);
  const int tile = swz & 15;
  const int n1i  = (swz >> 4) & 15;
  const int e    = swz >> 8;

  const int cnt  = counts[e];
  const int row0 = tile * 128;
  if (row0 >= cnt) return;
  const int nvalid = min(128, cnt - row0);
  const int n1  = n1i * 128;
  const int tid = threadIdx.x;
  const int wave = tid >> 6, lane = tid & 63;

  if (tid < 128) {
    int r = (tid < nvalid) ? tid : 0;
    int t = list[e * T_TOK + row0 + r];
    s_trow[tid] = t;
    s_wrow[tid] = w_te[t * N_EXP + e];
  }

  size_t aG[2], bG[2];
  unsigned ldsOff[2];
#pragma unroll
  for (int p = 0; p < 2; ++p) {
    int q = tid + p * 256;
    int r = q >> 2, c = q & 3;
    int sc = c ^ swz_m(r);
    ldsOff[p] = (unsigned)q * 8;
    int ra = (r < nvalid) ? r : 0;
    aG[p] = ((size_t)(e * T_TOK + row0 + ra) * I_DIM) * 2 + (size_t)(sc * 16);
    bG[p] = ((size_t)(e * H_DIM + n1 + r) * I_DIM) * 2 + (size_t)(sc * 16);
  }

  const int wm = wave >> 1, wn = wave & 1;
  const int kc = lane >> 4;
  unsigned aRd[4], bRd[4];
#pragma unroll
  for (int fr = 0; fr < 4; ++fr) {
    int R = wm * 64 + fr * 16 + (lane & 15);
    aRd[fr] = (unsigned)(R * 32 + (kc ^ swz_m(R)) * 8);
  }
#pragma unroll
  for (int fn = 0; fn < 4; ++fn) {
    int R = wn * 64 + fn * 16 + (lane & 15);
    bRd[fn] = (unsigned)(R * 32 + (kc ^ swz_m(R)) * 8);
  }

  f32x4 acc[4][4] = {};

#define STAGE2(buf, k0)                                                       \
  do {                                                                        \
    size_t kb = (size_t)(k0) * 2;                                             \
    _Pragma("unroll") for (int p = 0; p < 2; ++p) {                           \
      GLDS16((const char*)aq  + aG[p] + kb, &smem[buf][0][0] + ldsOff[p]);    \
      GLDS16((const char*)wdh + bG[p] + kb, &smem[buf][1][0] + ldsOff[p]);    \
    }                                                                         \
  } while (0)

  STAGE2(0, 0);
  __syncthreads();
  const int NT = I_DIM / 32;
  for (int t = 0; t < NT; ++t) {
    const int cur = t & 1;
    if (t + 1 < NT) STAGE2(cur ^ 1, (t + 1) * 32);
    const _Float16* sA = &smem[cur][0][0];
    const _Float16* sB = &smem[cur][1][0];
    half8 a[4], b[4];
#pragma unroll
    for (int fr = 0; fr < 4; ++fr) a[fr] = *(const half8*)(sA + aRd[fr]);
#pragma unroll
    for (int fn = 0; fn < 4; ++fn) b[fn] = *(const half8*)(sB + bRd[fn]);
#pragma unroll
    for (int fr = 0; fr < 4; ++fr)
#pragma unroll
      for (int fn = 0; fn < 4; ++fn)
        acc[fr][fn] = __builtin_amdgcn_mfma_f32_16x16x32_f16(a[fr], b[fn], acc[fr][fn], 0, 0, 0);
    __syncthreads();
  }
#undef STAGE2

#pragma unroll
  for (int fr = 0; fr < 4; ++fr) {
    int rb = wm * 64 + fr * 16 + (lane >> 4) * 4;
#pragma unroll
    for (int i = 0; i < 4; ++i) {
      int row = rb + i;
      if (row < nvalid) {
        int t = s_trow[row];
        float w = s_wrow[row];
#pragma unroll
        for (int fn = 0; fn < 4; ++fn) {
          int col = n1 + wn * 64 + fn * 16 + (lane & 15);
          unsafeAtomicAdd(&out[(size_t)t * H_DIM + col], w * acc[fr][fn][i]);
        }
      }
    }
  }
}

extern "C" void kernel_launch(void* const* d_in, const int* in_sizes, int n_in,
                              void* d_out, int out_size, void* d_ws, size_t ws_size,
                              hipStream_t stream) {
  const float* hs  = (const float*)d_in[0];
  const int*   tki = (const int*)d_in[1];
  const float* tkw = (const float*)d_in[2];
  const float* wgu = (const float*)d_in[3];
  const float* wd  = (const float*)d_in[4];
  float* out = (float*)d_out;

  char* ws = (char*)d_ws;
  size_t off = 0;
  auto alloc = [&](size_t bytes) -> void* {
    void* p = ws + off;
    off += bytes;
    off = (off + 255) & ~(size_t)255;
    return p;
  };
  int*      counts = (int*)alloc(N_EXP * 4);
  float*    w_te   = (float*)alloc((size_t)T_TOK * N_EXP * 4);
  int*      list   = (int*)alloc((size_t)N_EXP * T_TOK * 4);
  _Float16* xh     = (_Float16*)alloc((size_t)T_TOK * H_DIM * 2);
  _Float16* xl     = (_Float16*)alloc((size_t)T_TOK * H_DIM * 2);
  _Float16* wguh   = (_Float16*)alloc((size_t)N_EXP * 2 * I_DIM * H_DIM * 2);
  _Float16* wgul   = (_Float16*)alloc((size_t)N_EXP * 2 * I_DIM * H_DIM * 2);
  _Float16* wdh    = (_Float16*)alloc((size_t)N_EXP * H_DIM * I_DIM * 2);
  _Float16* aqb    = (_Float16*)alloc((size_t)N_EXP * T_TOK * I_DIM * 2);
  if (off > ws_size) return;

  zero_kernel<<<dim3(4096), dim3(256), 0, stream>>>(out, counts);
  router_kernel<<<dim3(8), dim3(256), 0, stream>>>(tki, tkw, w_te, counts, list);
  quant_kernel<<<dim3(4096), dim3(256), 0, stream>>>(hs, xh, xl, T_TOK * H_DIM / 4);
  quant_kernel<<<dim3(49152), dim3(256), 0, stream>>>(wgu, wguh, wgul, N_EXP * 2 * I_DIM * H_DIM / 4);
  quant_kernel<<<dim3(24576), dim3(256), 0, stream>>>(wd, wdh, (_Float16*)nullptr, N_EXP * H_DIM * I_DIM / 4);
  gemm1_kernel<<<dim3(3072), dim3(256), 0, stream>>>(xh, xl, wguh, wgul, counts, list, aqb);
  gemm2_kernel<<<dim3(4096), dim3(256), 0, stream>>>(aqb, wdh, counts, list, w_te, out);
}